// Round 1
// baseline (799.204 us; speedup 1.0000x reference)
//
#include <hip/hip_runtime.h>
#include <math.h>

#define B_  4
#define L_  8192
#define D_  512
#define TT  16
#define BL_ (B_*L_)

// ---------------------------------------------------------------------------
// Signal path: content = sigmoid(relu(x@W1+b1)@W2+b2)
//              pf      = grouped conv(x) + bc
//              bscore  = sigmoid(relu([x,pf]@Wb1+bb1)@Wb2+bb2)
//              signal  = content*(1-bscore)*mask
// One block = 16 tokens. Deterministic reduction order (no float atomics).
// ---------------------------------------------------------------------------
__global__ __launch_bounds__(256) void k_signal(
    const float* __restrict__ x, const float* __restrict__ mask,
    const float* __restrict__ W1, const float* __restrict__ b1,
    const float* __restrict__ W2, const float* __restrict__ b2,
    const float* __restrict__ Wc, const float* __restrict__ bc,
    const float* __restrict__ Wb1, const float* __restrict__ bb1,
    const float* __restrict__ Wb2, const float* __restrict__ bb2,
    float* __restrict__ signal)
{
  __shared__ float xs[TT + 2][D_];      // rows l0-1 .. l0+TT (zero padded)
  __shared__ float pfs[TT][256];
  __shared__ float part1[TT][32];
  __shared__ float part2[TT][32];

  const int tile = blockIdx.x;          // 2048 tiles, 512 per batch row
  const int b = tile >> 9;
  const int l0 = (tile & 511) * TT;
  const int t = threadIdx.x;
  const float* xb = x + (size_t)b * L_ * D_;

  // stage x rows [l0-1, l0+TT]  (18 rows x 512) as float4
  for (int i = t; i < (TT + 2) * (D_ / 4); i += 256) {
    int r  = i >> 7;                    // D_/4 == 128
    int c4 = i & 127;
    int l  = l0 - 1 + r;
    float4 v = make_float4(0.f, 0.f, 0.f, 0.f);
    if (l >= 0 && l < L_)
      v = reinterpret_cast<const float4*>(xb + (size_t)l * D_)[c4];
    reinterpret_cast<float4*>(&xs[r][0])[c4] = v;
  }
  __syncthreads();

  // grouped conv: output channel o = t (0..255), group g = o>>1, in chans 4g..4g+3
  {
    const int o  = t;
    const int g4 = (o >> 1) << 2;
    float wc[12];
#pragma unroll
    for (int i = 0; i < 12; ++i) wc[i] = Wc[o * 12 + i];
    const float bco = bc[o];
    for (int tok = 0; tok < TT; ++tok) {
      float acc = bco;
#pragma unroll
      for (int i = 0; i < 4; ++i)
#pragma unroll
        for (int k = 0; k < 3; ++k)
          acc = fmaf(xs[tok + k][g4 + i], wc[i * 3 + k], acc);
      pfs[tok][o] = acc;
    }
  }
  __syncthreads();

  // GEMMs: 16 tokens x 128 outputs; thread = (jq 0..31, tq 0..7) -> 2 tok x 4 j
  const int jq   = t & 31;
  const int tq   = t >> 5;
  const int j0   = jq << 2;
  const int tok0 = tq << 1;

  float a1[2][4] = {{0,0,0,0},{0,0,0,0}};
  float a2[2][4] = {{0,0,0,0},{0,0,0,0}};

#pragma unroll 4
  for (int k = 0; k < D_; ++k) {
    const float4 w1 = *reinterpret_cast<const float4*>(W1  + (k << 7) + j0);
    const float4 wb = *reinterpret_cast<const float4*>(Wb1 + (k << 7) + j0);
    const float x0 = xs[1 + tok0][k];
    const float x1 = xs[2 + tok0][k];
    a1[0][0] = fmaf(x0, w1.x, a1[0][0]); a1[0][1] = fmaf(x0, w1.y, a1[0][1]);
    a1[0][2] = fmaf(x0, w1.z, a1[0][2]); a1[0][3] = fmaf(x0, w1.w, a1[0][3]);
    a1[1][0] = fmaf(x1, w1.x, a1[1][0]); a1[1][1] = fmaf(x1, w1.y, a1[1][1]);
    a1[1][2] = fmaf(x1, w1.z, a1[1][2]); a1[1][3] = fmaf(x1, w1.w, a1[1][3]);
    a2[0][0] = fmaf(x0, wb.x, a2[0][0]); a2[0][1] = fmaf(x0, wb.y, a2[0][1]);
    a2[0][2] = fmaf(x0, wb.z, a2[0][2]); a2[0][3] = fmaf(x0, wb.w, a2[0][3]);
    a2[1][0] = fmaf(x1, wb.x, a2[1][0]); a2[1][1] = fmaf(x1, wb.y, a2[1][1]);
    a2[1][2] = fmaf(x1, wb.z, a2[1][2]); a2[1][3] = fmaf(x1, wb.w, a2[1][3]);
  }
#pragma unroll 4
  for (int k = 0; k < 256; ++k) {
    const float4 wb = *reinterpret_cast<const float4*>(Wb1 + ((512 + k) << 7) + j0);
    const float p0 = pfs[tok0][k];
    const float p1 = pfs[tok0 + 1][k];
    a2[0][0] = fmaf(p0, wb.x, a2[0][0]); a2[0][1] = fmaf(p0, wb.y, a2[0][1]);
    a2[0][2] = fmaf(p0, wb.z, a2[0][2]); a2[0][3] = fmaf(p0, wb.w, a2[0][3]);
    a2[1][0] = fmaf(p1, wb.x, a2[1][0]); a2[1][1] = fmaf(p1, wb.y, a2[1][1]);
    a2[1][2] = fmaf(p1, wb.z, a2[1][2]); a2[1][3] = fmaf(p1, wb.w, a2[1][3]);
  }

  // bias + relu + project to scalar partials (deterministic order)
  {
    float w2v[4], wv2[4], b1v[4], bbv[4];
#pragma unroll
    for (int jj = 0; jj < 4; ++jj) {
      w2v[jj] = W2[j0 + jj];  wv2[jj] = Wb2[j0 + jj];
      b1v[jj] = b1[j0 + jj];  bbv[jj] = bb1[j0 + jj];
    }
#pragma unroll
    for (int i = 0; i < 2; ++i) {
      float p1s = 0.f, p2s = 0.f;
#pragma unroll
      for (int jj = 0; jj < 4; ++jj) {
        float h1 = a1[i][jj] + b1v[jj];
        if (h1 > 0.f) p1s = fmaf(h1, w2v[jj], p1s);
        float h2 = a2[i][jj] + bbv[jj];
        if (h2 > 0.f) p2s = fmaf(h2, wv2[jj], p2s);
      }
      part1[tok0 + i][jq] = p1s;
      part2[tok0 + i][jq] = p2s;
    }
  }
  __syncthreads();

  if (t < TT) {
    float z1 = b2[0], z2 = bb2[0];
    for (int q = 0; q < 32; ++q) { z1 += part1[t][q]; z2 += part2[t][q]; }
    const float content = 1.f / (1.f + expf(-z1));
    const float bscore  = 1.f / (1.f + expf(-z2));
    const int gi = b * L_ + l0 + t;
    signal[gi] = content * (1.f - bscore) * mask[gi];
  }
}

// ---------------------------------------------------------------------------
// Exact 0.7-quantile per row via MSB-first radix select on monotonic keys.
// ---------------------------------------------------------------------------
__global__ __launch_bounds__(256) void k_quantile(const float* __restrict__ signal,
                                                  float* __restrict__ thr)
{
  __shared__ unsigned int bins[256];
  __shared__ unsigned int sh_prefix;
  __shared__ int sh_rank;
  __shared__ unsigned int keys_out[2];
  const int b = blockIdx.x, t = threadIdx.x;
  const float* s = signal + b * L_;
  const int rank0 = 5733;   // floor(0.7*(L-1)) for L=8192

  for (int which = 0; which < 2; ++which) {
    if (t == 0) { sh_prefix = 0u; sh_rank = rank0 + which; }
    __syncthreads();
    for (int round = 0; round < 4; ++round) {
      bins[t] = 0u;
      __syncthreads();
      const unsigned int pre = sh_prefix;
      const int shift = 24 - 8 * round;
      for (int i = t; i < L_; i += 256) {
        unsigned int u = __float_as_uint(s[i]);
        unsigned int key = (u & 0x80000000u) ? ~u : (u | 0x80000000u);
        if (round == 0) {
          atomicAdd(&bins[key >> 24], 1u);
        } else if ((key >> (shift + 8)) == pre) {
          atomicAdd(&bins[(key >> shift) & 255u], 1u);
        }
      }
      __syncthreads();
      if (t == 0) {
        int r = sh_rank;
        unsigned int c = 0;
        while (r >= (int)bins[c]) { r -= (int)bins[c]; ++c; }
        sh_rank = r;
        sh_prefix = (pre << 8) | c;
      }
      __syncthreads();
    }
    if (t == 0) keys_out[which] = sh_prefix;
    __syncthreads();
  }
  if (t == 0) {
    unsigned int k0 = keys_out[0], k1 = keys_out[1];
    unsigned int u0 = (k0 & 0x80000000u) ? (k0 & 0x7fffffffu) : ~k0;
    unsigned int u1 = (k1 & 0x80000000u) ? (k1 & 0x7fffffffu) : ~k1;
    double v0 = (double)__uint_as_float(u0);
    double v1 = (double)__uint_as_float(u1);
    double g = 0.7 * (double)(L_ - 1) - (double)rank0;
    thr[b] = (float)(v0 + g * (v1 - v0));
  }
}

// ---------------------------------------------------------------------------
// Greedy enforce + splits + prefix scan -> segment starts, n_last, seg_bounds.
// ---------------------------------------------------------------------------
__global__ __launch_bounds__(256) void k_enforce(
    const float* __restrict__ signal, const float* __restrict__ thr_arr,
    int* __restrict__ starts, int* __restrict__ nlast, float* __restrict__ bounds)
{
  __shared__ unsigned long long cw[L_ / 64];
  __shared__ unsigned char nb[L_];
  __shared__ int tsum[256];
  __shared__ int offs[257];
  const int b = blockIdx.x, t = threadIdx.x;
  const float thr = thr_arr[b];
  const float* s = signal + b * L_;

  if (t < L_ / 64) {
    unsigned long long w = 0ull;
    const int p0 = t << 6;
    for (int i = 0; i < 64; ++i)
      if (s[p0 + i] < thr) w |= (1ull << i);
    if (t == L_ / 64 - 1) w |= (1ull << 63);   // forced candidate at L-1
    cw[t] = w;
  }
  {
    const int base = t * (L_ / 256);
    for (int i = 0; i < L_ / 256; ++i) nb[base + i] = 0;
  }
  __syncthreads();

  if (t == 0) {
    int st = 0;
    for (;;) {
      const int from = st + 4;
      if (from >= L_) break;
      int wi = from >> 6;
      unsigned long long w = cw[wi] & (~0ull << (from & 63));
      while (w == 0ull) {
        if (++wi >= L_ / 64) break;
        w = cw[wi];
      }
      if (w == 0ull) break;
      const int p  = (wi << 6) + (__ffsll((unsigned long long)w) - 1);
      const int ps = p - st;
      nb[p] = 1;
      const int k = (ps + 15) >> 4;
      if (k > 1) {
        int sz = ps / k; if (sz < 1) sz = 1;
        for (int j = 1; j < k; ++j) nb[st + j * sz] = 1;
      }
      st = p;
    }
  }
  __syncthreads();

  const int base = t * 32;
  int ls = 0;
  for (int i = 0; i < 32; ++i) ls += nb[base + i];
  tsum[t] = ls;
  __syncthreads();
  if (t == 0) {
    int r = 0;
    for (int i = 0; i < 256; ++i) { offs[i] = r; r += tsum[i]; }
    offs[256] = r;
  }
  __syncthreads();

  int run = offs[t];
  for (int i = 0; i < 32; ++i) {
    run += nb[base + i];
    if (nb[base + i]) starts[b * L_ + run] = base + i;
  }
  if (t == 0) { starts[b * L_ + 0] = 0; nlast[b] = offs[256]; }
  const int total = offs[256];
  for (int i = t; i < L_; i += 256) {
    bounds[b * L_ + i] = (i >= 1 && i <= total) ? 1.0f : 0.0f;
  }
}

// ---------------------------------------------------------------------------
// e[tok] = sum_d (x*mask)^2  — one wave per token, tree reduce.
// ---------------------------------------------------------------------------
__global__ __launch_bounds__(256) void k_e(const float* __restrict__ x,
                                           const float* __restrict__ mask,
                                           float* __restrict__ e)
{
  const int wave = threadIdx.x >> 6, lane = threadIdx.x & 63;
  const int tok = (blockIdx.x << 2) + wave;
  const float m = mask[tok];
  const float* xr = x + (size_t)tok * D_ + (lane << 3);
  const float4 v0 = reinterpret_cast<const float4*>(xr)[0];
  const float4 v1 = reinterpret_cast<const float4*>(xr)[1];
  float acc = 0.f, q;
  q = v0.x * m; acc = fmaf(q, q, acc);
  q = v0.y * m; acc = fmaf(q, q, acc);
  q = v0.z * m; acc = fmaf(q, q, acc);
  q = v0.w * m; acc = fmaf(q, q, acc);
  q = v1.x * m; acc = fmaf(q, q, acc);
  q = v1.y * m; acc = fmaf(q, q, acc);
  q = v1.z * m; acc = fmaf(q, q, acc);
  q = v1.w * m; acc = fmaf(q, q, acc);
#pragma unroll
  for (int off = 32; off > 0; off >>= 1) acc += __shfl_down(acc, off, 64);
  if (lane == 0) e[tok] = acc;
}

// ---------------------------------------------------------------------------
// Segment softmax-merge: one wave per segment id (contiguous token range).
// ---------------------------------------------------------------------------
__global__ __launch_bounds__(64) void k_merge(const float* __restrict__ x,
    const float* __restrict__ mask, const float* __restrict__ e,
    const int* __restrict__ starts, const int* __restrict__ nlast,
    float* __restrict__ merged)
{
  const int idx = blockIdx.x;
  const int b   = idx >> 13;            // L_ == 8192
  const int sid = idx & (L_ - 1);
  const int n = nlast[b];
  if (sid > n) return;                  // rows pre-zeroed
  const int t0 = starts[b * L_ + sid];
  const int t1 = (sid < n) ? starts[b * L_ + sid + 1] : L_;
  const float* eb = e + b * L_;

  float mx = -INFINITY;
  for (int p = t0; p < t1; ++p) mx = fmaxf(mx, eb[p]);
  float den = 0.f;
  for (int p = t0; p < t1; ++p) den += expf(eb[p] - mx);

  const int lane = threadIdx.x;
  const int c0 = lane << 3;
  float acc[8] = {0,0,0,0,0,0,0,0};
  for (int p = t0; p < t1; ++p) {
    const float wn = expf(eb[p] - mx) / den;
    const float sc = wn * mask[b * L_ + p];
    const float* xr = x + ((size_t)(b * L_ + p)) * D_ + c0;
    const float4 u0 = reinterpret_cast<const float4*>(xr)[0];
    const float4 u1 = reinterpret_cast<const float4*>(xr)[1];
    acc[0] = fmaf(sc, u0.x, acc[0]); acc[1] = fmaf(sc, u0.y, acc[1]);
    acc[2] = fmaf(sc, u0.z, acc[2]); acc[3] = fmaf(sc, u0.w, acc[3]);
    acc[4] = fmaf(sc, u1.x, acc[4]); acc[5] = fmaf(sc, u1.y, acc[5]);
    acc[6] = fmaf(sc, u1.z, acc[6]); acc[7] = fmaf(sc, u1.w, acc[7]);
  }
  float* o = merged + (size_t)(b * L_ + sid) * D_ + c0;
  reinterpret_cast<float4*>(o)[0] = make_float4(acc[0], acc[1], acc[2], acc[3]);
  reinterpret_cast<float4*>(o)[1] = make_float4(acc[4], acc[5], acc[6], acc[7]);
}

// ---------------------------------------------------------------------------
extern "C" void kernel_launch(void* const* d_in, const int* in_sizes, int n_in,
                              void* d_out, int out_size, void* d_ws, size_t ws_size,
                              hipStream_t stream) {
  (void)in_sizes; (void)n_in; (void)out_size; (void)ws_size;
  const float* x    = (const float*)d_in[0];
  const float* mask = (const float*)d_in[1];
  const float* W1   = (const float*)d_in[2];
  const float* b1   = (const float*)d_in[3];
  const float* W2   = (const float*)d_in[4];
  const float* b2   = (const float*)d_in[5];
  const float* Wc   = (const float*)d_in[6];
  const float* bc   = (const float*)d_in[7];
  const float* Wb1  = (const float*)d_in[8];
  const float* bb1  = (const float*)d_in[9];
  const float* Wb2  = (const float*)d_in[10];
  const float* bb2  = (const float*)d_in[11];

  float* merged = (float*)d_out;
  float* bounds = (float*)d_out + (size_t)BL_ * D_;

  char* ws = (char*)d_ws;
  float* signal = (float*)(ws);
  float* e      = (float*)(ws + (size_t)BL_ * 4);
  int*   starts = (int*)  (ws + (size_t)BL_ * 8);
  int*   nlast  = (int*)  (ws + (size_t)BL_ * 12);
  float* thr    = (float*)(ws + (size_t)BL_ * 12 + 64);

  hipMemsetAsync(merged, 0, (size_t)BL_ * D_ * sizeof(float), stream);

  k_signal<<<BL_ / TT, 256, 0, stream>>>(x, mask, W1, b1, W2, b2, Wc, bc,
                                         Wb1, bb1, Wb2, bb2, signal);
  k_quantile<<<B_, 256, 0, stream>>>(signal, thr);
  k_enforce<<<B_, 256, 0, stream>>>(signal, thr, starts, nlast, bounds);
  k_e<<<BL_ / 4, 256, 0, stream>>>(x, mask, e);
  k_merge<<<BL_, 64, 0, stream>>>(x, mask, e, starts, nlast, merged);
}